// Round 1
// baseline (306.706 us; speedup 1.0000x reference)
//
#include <hip/hip_runtime.h>
#include <math.h>

#define BB 4
#define SS 4096
#define DD 128
#define NSPK 9
#define WIN 15
#define BANDW 31          // 2*WIN+1
#define EPSN 1e-8f
#define INV_PI 0.31830988618379067f

// ---------------------------------------------------------------------------
// k_prep: one wave (64 lanes) per row (b,s).
//   - lane l loads x[row, 2l:2l+2], butterfly-reduce sum of squares
//   - write normalized row xn = x / max(||x||, eps)
//   - lane 0 computes speaker[row] = argmax_k qmask[s, b, k] (first max)
// ---------------------------------------------------------------------------
__global__ __launch_bounds__(256) void k_prep(const float* __restrict__ x,
                                              const float* __restrict__ qmask,
                                              float* __restrict__ xn,
                                              int* __restrict__ spk) {
    int wid  = (blockIdx.x * blockDim.x + threadIdx.x) >> 6;  // row = b*S + s
    int lane = threadIdx.x & 63;
    if (wid >= BB * SS) return;

    const float2* xr = (const float2*)(x + (size_t)wid * DD);
    float2 v = xr[lane];
    float ss = v.x * v.x + v.y * v.y;
    #pragma unroll
    for (int off = 32; off; off >>= 1) ss += __shfl_xor(ss, off);
    float inv = 1.0f / fmaxf(sqrtf(ss), EPSN);
    float2 o; o.x = v.x * inv; o.y = v.y * inv;
    ((float2*)(xn + (size_t)wid * DD))[lane] = o;

    if (lane == 0) {
        int b = wid / SS, s = wid % SS;
        const float* q = qmask + ((size_t)s * BB + b) * NSPK;
        float best = q[0]; int bi = 0;
        #pragma unroll
        for (int k = 1; k < NSPK; ++k) {
            float qv = q[k];
            if (qv > best) { best = qv; bi = k; }   // strict > : first-max tie-break
        }
        spk[wid] = bi;
    }
}

// ---------------------------------------------------------------------------
// k_band: one wave per row i. Lane l in [0,31) handles neighbor j = i-15+l.
//   - fp32 dot(xn_i, xn_j) over D=128 (xi loads wave-uniform, xj per-lane)
//   - w = 1 - acos(clip(dot))/pi, masked by window & validity
//   - cnt = popcount(ballot(mask & same-speaker)); doubling if cnt>1 & same
//   - deg = wave-sum; store band value and dinv = (deg?deg:1)^-0.5
// ---------------------------------------------------------------------------
__global__ __launch_bounds__(256) void k_band(const float* __restrict__ xn,
                                              const int* __restrict__ spk,
                                              const int* __restrict__ dia_len,
                                              float* __restrict__ band,
                                              float* __restrict__ dinv) {
    int row  = (blockIdx.x * blockDim.x + threadIdx.x) >> 6;
    int lane = threadIdx.x & 63;
    if (row >= BB * SS) return;
    int b = row / SS, i = row % SS;
    int len = dia_len[b];
    int j = i - WIN + lane;
    bool inr   = (lane < BANDW) && (j >= 0) && (j < SS);
    bool maskv = inr && (i < len) && (j < len);

    bool same = false;
    if (inr) same = (spk[row] == spk[b * SS + j]);

    float aij = 0.f;
    if (maskv) {
        const float4* xi = (const float4*)(xn + (size_t)row * DD);
        const float4* xj = (const float4*)(xn + ((size_t)b * SS + j) * DD);
        float d0 = 0.f, d1 = 0.f;
        #pragma unroll
        for (int d = 0; d < DD / 8; ++d) {
            float4 a0 = xi[2 * d],     c0 = xj[2 * d];
            float4 a1 = xi[2 * d + 1], c1 = xj[2 * d + 1];
            d0 += a0.x * c0.x + a0.y * c0.y + a0.z * c0.z + a0.w * c0.w;
            d1 += a1.x * c1.x + a1.y * c1.y + a1.z * c1.z + a1.w * c1.w;
        }
        float dot = d0 + d1;
        dot = fminf(fmaxf(dot, -1.f), 1.f);
        aij = 1.f - acosf(dot) * INV_PI;
    }

    unsigned long long bal = __ballot(maskv && same);
    int cnt = __popcll(bal);
    if (maskv && same && cnt > 1) aij *= 2.f;

    float deg = aij;
    #pragma unroll
    for (int off = 32; off; off >>= 1) deg += __shfl_xor(deg, off);

    if (lane < 32) band[(size_t)row * 32 + lane] = aij;   // lane 31 writes 0
    if (lane == 0) {
        float dv = (deg == 0.f) ? 1.f : deg;
        dinv[row] = 1.0f / sqrtf(dv);
    }
}

// ---------------------------------------------------------------------------
// k_write: thread per (row, l), l in [0,32). Writes the 31 banded entries of
// each output row, scaled by dinv_i * dinv_j. Rest of out already memset to 0.
// ---------------------------------------------------------------------------
__global__ __launch_bounds__(256) void k_write(const float* __restrict__ band,
                                               const float* __restrict__ dinv,
                                               float* __restrict__ out) {
    int t = blockIdx.x * blockDim.x + threadIdx.x;
    int row = t >> 5, l = t & 31;
    if (row >= BB * SS) return;
    int b = row / SS, i = row % SS;
    int j = i - WIN + l;
    if (l < BANDW && j >= 0 && j < SS) {
        float v = band[(size_t)row * 32 + l] * dinv[row] * dinv[b * SS + j];
        out[(size_t)row * SS + j] = v;
    }
}

extern "C" void kernel_launch(void* const* d_in, const int* in_sizes, int n_in,
                              void* d_out, int out_size, void* d_ws, size_t ws_size,
                              hipStream_t stream) {
    const float* x       = (const float*)d_in[0];
    const float* qmask   = (const float*)d_in[1];
    const int*   dia_len = (const int*)d_in[2];
    float* out = (float*)d_out;

    char* ws = (char*)d_ws;
    const size_t rows = (size_t)BB * SS;
    float* xn   = (float*)ws;                                   // rows*D floats (8.4 MB)
    int*   spk  = (int*)  (ws + rows * DD * 4);                 // rows ints
    float* dinv = (float*)(ws + rows * DD * 4 + rows * 4);      // rows floats
    float* band = (float*)(ws + rows * DD * 4 + 2 * rows * 4);  // rows*32 floats (2.1 MB)

    // zero the full [B,S,S] output (it is poisoned before every timed call)
    hipMemsetAsync(d_out, 0, (size_t)out_size * sizeof(float), stream);

    int nrows = BB * SS;
    k_prep <<<nrows / 4, 256, 0, stream>>>(x, qmask, xn, spk);
    k_band <<<nrows / 4, 256, 0, stream>>>(xn, spk, dia_len, band, dinv);
    k_write<<<nrows * 32 / 256, 256, 0, stream>>>(band, dinv, out);
}